// Round 9
// baseline (110.374 us; speedup 1.0000x reference)
//
#include <hip/hip_runtime.h>

#define FEAT   256
#define K2     512      // 2*FEAT
#define NNODES 100000
#define BATCH  50000
#define NS     10
#define EMBED  256
#define BN     32
#define NBLK   ((BATCH + BN - 1) / BN)   // 1563
#define NSH    8        // column shards (one per XCD)
#define SHC    32       // fp8 cols per shard

typedef __attribute__((ext_vector_type(8))) __bf16         bf16x8;
typedef __attribute__((ext_vector_type(8))) unsigned short ushort8;
typedef __attribute__((ext_vector_type(4))) float          f32x4;
typedef __attribute__((ext_vector_type(2))) float          f32x2;
typedef __attribute__((ext_vector_type(2))) int            i32x2;
typedef __attribute__((ext_vector_type(4))) int            i32x4;

static __device__ __forceinline__ unsigned short f2bf(float x) {
    unsigned int u = __builtin_bit_cast(unsigned int, x);
    u += 0x7FFFu + ((u >> 16) & 1u);
    return (unsigned short)(u >> 16);
}
static __device__ __forceinline__ float bf2f(unsigned short h) {
    return __builtin_bit_cast(float, (unsigned int)h << 16);
}
static __device__ __forceinline__ void gload16(void* lds, const void* g) {
    __builtin_amdgcn_global_load_lds(
        (const __attribute__((address_space(1))) void*)g,
        (__attribute__((address_space(3))) void*)lds, 16, 0, 0);
}

// ---- features f32 -> bf16 table + fp8 table (SHARD: column-sharded layout) ----
template <bool SHARD>
__global__ void fconv_kernel(const float* __restrict__ f,
                             unsigned short* __restrict__ fb,
                             unsigned char* __restrict__ f8) {
    int i = blockIdx.x * blockDim.x + threadIdx.x;   // one 8-elem chunk
    const f32x4* src = (const f32x4*)(f + (size_t)i * 8);
    f32x4 a = __builtin_nontemporal_load(src);
    f32x4 b = __builtin_nontemporal_load(src + 1);
    ushort8 h;
    h[0]=f2bf(a[0]); h[1]=f2bf(a[1]); h[2]=f2bf(a[2]); h[3]=f2bf(a[3]);
    h[4]=f2bf(b[0]); h[5]=f2bf(b[1]); h[6]=f2bf(b[2]); h[7]=f2bf(b[3]);
    ((ushort8*)fb)[i] = h;
    int u0 = 0, u1 = 0;
    u0 = __builtin_amdgcn_cvt_pk_fp8_f32(a[0], a[1], u0, false);
    u0 = __builtin_amdgcn_cvt_pk_fp8_f32(a[2], a[3], u0, true);
    u1 = __builtin_amdgcn_cvt_pk_fp8_f32(b[0], b[1], u1, false);
    u1 = __builtin_amdgcn_cvt_pk_fp8_f32(b[2], b[3], u1, true);
    i32x2 p; p[0] = u0; p[1] = u1;
    if (SHARD) {
        int node = i >> 5, c8 = i & 31;
        int shard = c8 >> 2, off = (c8 & 3) * 8;
        *(i32x2*)(f8 + ((size_t)shard * NNODES + node) * SHC + off) = p;
    } else {
        ((i32x2*)f8)[i] = p;
    }
}

// ---- weight f32 -> bf16, fragment-major: [kt(8)][mblk(16)][ks(2)][lane(64)][8] ----
__global__ void wpack_kernel(const float* __restrict__ w,
                             unsigned short* __restrict__ wp) {
    int c    = blockIdx.x * blockDim.x + threadIdx.x;  // 16384 chunks
    int lane = c & 63;
    int ks   = (c >> 6) & 1;
    int mblk = (c >> 7) & 15;
    int kt   = c >> 11;
    int row  = mblk * 16 + (lane & 15);
    int col  = kt * 64 + ks * 32 + (lane >> 4) * 8;
    const f32x4* src = (const f32x4*)(w + row * K2 + col);
    f32x4 a = src[0], b = src[1];
    ushort8 h;
    h[0]=f2bf(a[0]); h[1]=f2bf(a[1]); h[2]=f2bf(a[2]); h[3]=f2bf(a[3]);
    h[4]=f2bf(b[0]); h[5]=f2bf(b[1]); h[6]=f2bf(b[2]); h[7]=f2bf(b[3]);
    ((ushort8*)wp)[c] = h;
}

// ---- neighbor mean, XCD-pinned shard: block bid -> shard = bid&7 (== XCD) ----
// each thread: one (row n, 8-col piece) -> 10 x 8B L2-resident loads -> 16B nt store
__global__ __launch_bounds__(256, 8) void nmean_kernel(
    const unsigned char* __restrict__ f8s,
    const int* __restrict__ neigh,
    unsigned short* __restrict__ nm) {
    const int shard = blockIdx.x & 7;
    const int n     = (blockIdx.x >> 3) * 64 + (threadIdx.x >> 2);
    const int piece = threadIdx.x & 3;
    if (n >= BATCH) return;
    const unsigned char* tab = f8s + (size_t)shard * NNODES * SHC + piece * 8;

    int idx[NS];
    #pragma unroll
    for (int s = 0; s < NS; ++s)
        idx[s] = __builtin_nontemporal_load(&neigh[n * NS + s]);

    float acc[8];
    #pragma unroll
    for (int e = 0; e < 8; ++e) acc[e] = 0.f;
    #pragma unroll
    for (int s = 0; s < NS; ++s) {
        i32x2 v = *(const i32x2*)(tab + (size_t)idx[s] * SHC);
        #pragma unroll
        for (int q = 0; q < 2; ++q) {
            f32x2 lo = __builtin_amdgcn_cvt_pk_f32_fp8(v[q], false);
            f32x2 hi = __builtin_amdgcn_cvt_pk_f32_fp8(v[q], true);
            acc[q * 4 + 0] += lo[0];
            acc[q * 4 + 1] += lo[1];
            acc[q * 4 + 2] += hi[0];
            acc[q * 4 + 3] += hi[1];
        }
    }
    ushort8 o;
    #pragma unroll
    for (int e = 0; e < 8; ++e) o[e] = f2bf(acc[e] * 0.1f);
    __builtin_nontemporal_store(o,
        (ushort8*)(nm + ((size_t)shard * BATCH + n) * SHC + piece * 8));
}

// ---- fused: self DMA + sequential nm read -> LDS tile -> MFMA -> relu ----
__global__ __launch_bounds__(512, 4) void gemm_xcd(
    const unsigned short* __restrict__ fbf,
    const unsigned short* __restrict__ nm_,
    const unsigned short* __restrict__ wp,
    const int* __restrict__ nodes,
    float* __restrict__ out) {

    __shared__ __align__(16) unsigned short lB[BN * K2];   // 32 KB

    const int tid  = threadIdx.x;
    const int nb0  = blockIdx.x * BN;
    const int w    = tid >> 6;
    const int lane = tid & 63;
    const char* fbb = (const char*)fbf;

    // nm sequential read: wave w = shard w; lane covers (row = lane>>1, 16-col half)
    const int r_nm = lane >> 1;
    const int n_nm = min(nb0 + r_nm, BATCH - 1);
    const ushort8* nmp = (const ushort8*)(nm_ +
        ((size_t)w * BATCH + n_nm) * SHC + (lane & 1) * 16);
    ushort8 d0 = nmp[0], d1 = nmp[1];

    // self rows: DMA rows 4w..4w+3 into lB cols 0..255 (pre-swizzled source)
    int off_s[4];
    #pragma unroll
    for (int j = 0; j < 4; ++j)
        off_s[j] = nodes[min(nb0 + 4 * w + j, BATCH - 1)] << 9;
    #pragma unroll
    for (int j = 0; j < 4; ++j) {
        const int r = 4 * w + j, rx = r & 7;
        if (lane < 32) {
            const int cs = (lane & ~7) | ((lane & 7) ^ rx);
            gload16(&lB[r * K2], fbb + off_s[j] + cs * 16);
        }
    }
    __builtin_amdgcn_sched_barrier(0);   // keep DMA issues ahead of nm LDS writes

    // nm -> lB neighbor half (groups 4..7, swizzled chunks)
    {
        const int rx = r_nm & 7;
        const int g  = 4 + (w >> 1);
        const int i0 = (w & 1) * 4 + (lane & 1) * 2;
        unsigned short* dst = lB + r_nm * K2 + g * 64;
        *(ushort8*)&dst[((i0    ) ^ rx) * 8] = d0;
        *(ushort8*)&dst[((i0 + 1) ^ rx) * 8] = d1;
    }
    asm volatile("s_waitcnt vmcnt(0)" ::: "memory");
    __syncthreads();

    // MFMA: wave w -> m rows [w*32, w*32+32), all 32 n-cols
    const int lr = lane & 15;
    const int lg = lane >> 4;
    f32x4 facc[2][2] = {};

    #pragma unroll
    for (int kt = 0; kt < 8; ++kt) {
        bf16x8 af[2][2], bfr[2][2];
        #pragma unroll
        for (int i = 0; i < 2; ++i)
            #pragma unroll
            for (int ks = 0; ks < 2; ++ks)
                af[i][ks] = *(const bf16x8*)(wp +
                    ((((kt * 16 + w * 2 + i) * 2 + ks) * 64 + lane) << 3));
        #pragma unroll
        for (int j = 0; j < 2; ++j) {
            const int rb = j * 16 + lr;
            #pragma unroll
            for (int ks = 0; ks < 2; ++ks) {
                int cc = kt * 8 + ((ks * 4 + lg) ^ (rb & 7));
                bfr[j][ks] = *(const bf16x8*)&lB[rb * K2 + cc * 8];
            }
        }
        #pragma unroll
        for (int ks = 0; ks < 2; ++ks)
            #pragma unroll
            for (int i = 0; i < 2; ++i)
                #pragma unroll
                for (int j = 0; j < 2; ++j)
                    facc[i][j] = __builtin_amdgcn_mfma_f32_16x16x32_bf16(
                        af[i][ks], bfr[j][ks], facc[i][j], 0, 0, 0);
    }

    #pragma unroll
    for (int j = 0; j < 2; ++j) {
        const int n2 = nb0 + j * 16 + lr;
        if (n2 < BATCH) {
            #pragma unroll
            for (int i = 0; i < 2; ++i) {
                int m0 = w * 32 + i * 16 + lg * 4;
                #pragma unroll
                for (int rg = 0; rg < 4; ++rg) {
                    float v = facc[i][j][rg];
                    v = v > 0.f ? v : 0.f;
                    __builtin_nontemporal_store(v, &out[(size_t)(m0 + rg) * BATCH + n2]);
                }
            }
        }
    }
}

// ---- tier-2: R8 fused fp8 pipeline (linear f8 table) ----
__global__ __launch_bounds__(512, 4) void gemm_dma(
    const unsigned short* __restrict__ fbf,
    const unsigned char* __restrict__ ffp8,
    const unsigned short* __restrict__ wp,
    const int* __restrict__ nodes,
    const int* __restrict__ neigh,
    float* __restrict__ out) {

    __shared__ __align__(16) unsigned short lB[BN * K2];
    __shared__ __align__(16) unsigned char  s8[3][BN * FEAT];

    const int tid  = threadIdx.x;
    const int nb0  = blockIdx.x * BN;
    const int w    = tid >> 6;
    const int lane = tid & 63;
    const char* fbb = (const char*)fbf;
    const char* f8b = (const char*)ffp8;

    int off_s[4];
    #pragma unroll
    for (int j = 0; j < 4; ++j)
        off_s[j] = nodes[min(nb0 + 4 * w + j, BATCH - 1)] << 9;
    const int nrow = min(nb0 + 4 * w + (lane >> 4), BATCH - 1);
    int on[NS];
    #pragma unroll
    for (int s = 0; s < NS; ++s)
        on[s] = neigh[nrow * NS + s] << 8;
    asm volatile("s_waitcnt vmcnt(0)" ::: "memory");

    #pragma unroll
    for (int j = 0; j < 4; ++j) {
        const int r = 4 * w + j, rx = r & 7;
        if (lane < 32) {
            const int cs = (lane & ~7) | ((lane & 7) ^ rx);
            gload16(&lB[r * K2], fbb + off_s[j] + cs * 16);
        }
    }
    #pragma unroll
    for (int s = 0; s < 3; ++s)
        gload16(&s8[s][w * 1024], f8b + on[s] + (lane & 15) * 16);

    const int cr  = tid >> 4;
    const int ch  = tid & 15;
    const int crx = cr & 7;
    float acc[16];
    #pragma unroll
    for (int e = 0; e < 16; ++e) acc[e] = 0.f;

    #pragma unroll
    for (int s = 0; s < NS; ++s) {
        if (s <= 7)      asm volatile("s_waitcnt vmcnt(2)" ::: "memory");
        else if (s == 8) asm volatile("s_waitcnt vmcnt(1)" ::: "memory");
        else             asm volatile("s_waitcnt vmcnt(0)" ::: "memory");
        __builtin_amdgcn_s_barrier();
        __builtin_amdgcn_sched_barrier(0);

        i32x4 v = *(const i32x4*)&s8[s % 3][cr * 256 + ch * 16];
        #pragma unroll
        for (int q = 0; q < 4; ++q) {
            f32x2 lo = __builtin_amdgcn_cvt_pk_f32_fp8(v[q], false);
            f32x2 hi = __builtin_amdgcn_cvt_pk_f32_fp8(v[q], true);
            acc[q * 4 + 0] += lo[0];
            acc[q * 4 + 1] += lo[1];
            acc[q * 4 + 2] += hi[0];
            acc[q * 4 + 3] += hi[1];
        }
        __builtin_amdgcn_sched_barrier(0);
        __builtin_amdgcn_s_barrier();
        __builtin_amdgcn_sched_barrier(0);
        if (s + 3 < NS)
            gload16(&s8[s % 3][w * 1024], f8b + on[s + 3] + (lane & 15) * 16);
    }
    {
        ushort8 a, b;
        #pragma unroll
        for (int e = 0; e < 8; ++e) {
            a[e] = f2bf(acc[e] * 0.1f);
            b[e] = f2bf(acc[8 + e] * 0.1f);
        }
        const int g = 4 + (ch >> 2), i0 = (ch & 3) * 2;
        unsigned short* dst = lB + cr * K2 + g * 64;
        *(ushort8*)&dst[((i0    ) ^ crx) * 8] = a;
        *(ushort8*)&dst[((i0 + 1) ^ crx) * 8] = b;
    }
    __syncthreads();

    const int lr = lane & 15;
    const int lg = lane >> 4;
    f32x4 facc[2][2] = {};
    #pragma unroll
    for (int kt = 0; kt < 8; ++kt) {
        bf16x8 af[2][2], bfr[2][2];
        #pragma unroll
        for (int i = 0; i < 2; ++i)
            #pragma unroll
            for (int ks = 0; ks < 2; ++ks)
                af[i][ks] = *(const bf16x8*)(wp +
                    ((((kt * 16 + w * 2 + i) * 2 + ks) * 64 + lane) << 3));
        #pragma unroll
        for (int j = 0; j < 2; ++j) {
            const int rb = j * 16 + lr;
            #pragma unroll
            for (int ks = 0; ks < 2; ++ks) {
                int cc = kt * 8 + ((ks * 4 + lg) ^ (rb & 7));
                bfr[j][ks] = *(const bf16x8*)&lB[rb * K2 + cc * 8];
            }
        }
        #pragma unroll
        for (int ks = 0; ks < 2; ++ks)
            #pragma unroll
            for (int i = 0; i < 2; ++i)
                #pragma unroll
                for (int j = 0; j < 2; ++j)
                    facc[i][j] = __builtin_amdgcn_mfma_f32_16x16x32_bf16(
                        af[i][ks], bfr[j][ks], facc[i][j], 0, 0, 0);
    }
    #pragma unroll
    for (int j = 0; j < 2; ++j) {
        const int n2 = nb0 + j * 16 + lr;
        if (n2 < BATCH) {
            #pragma unroll
            for (int i = 0; i < 2; ++i) {
                int m0 = w * 32 + i * 16 + lg * 4;
                #pragma unroll
                for (int rg = 0; rg < 4; ++rg) {
                    float v = facc[i][j][rg];
                    v = v > 0.f ? v : 0.f;
                    __builtin_nontemporal_store(v, &out[(size_t)(m0 + rg) * BATCH + n2]);
                }
            }
        }
    }
}

// ---- tier-3: f32 fallback ----
__global__ __launch_bounds__(512, 4) void gemm_f32(
    const float* __restrict__ features,
    const unsigned short* __restrict__ wp,
    const int* __restrict__ nodes,
    const int* __restrict__ neigh,
    float* __restrict__ out) {

    __shared__ __align__(16) unsigned short lB[BN * K2];

    const int tid = threadIdx.x;
    const int nb0 = blockIdx.x * BN;
    const int r  = tid >> 4;
    const int h  = tid & 15;
    const int rx = r & 7;
    const int n  = nb0 + r;
    const bool valid = n < BATCH;

    int node0 = valid ? nodes[n] : 0;
    int nidx[NS];
    #pragma unroll
    for (int s = 0; s < NS; ++s) nidx[s] = valid ? neigh[n * NS + s] : 0;

    ushort8 a = {0,0,0,0,0,0,0,0}, b = a;
    if (valid) {
        const f32x4* s0 = (const f32x4*)(features + (size_t)node0 * FEAT + h * 16);
        f32x4 x0 = s0[0], x1 = s0[1], x2 = s0[2], x3 = s0[3];
        a[0]=f2bf(x0[0]); a[1]=f2bf(x0[1]); a[2]=f2bf(x0[2]); a[3]=f2bf(x0[3]);
        a[4]=f2bf(x1[0]); a[5]=f2bf(x1[1]); a[6]=f2bf(x1[2]); a[7]=f2bf(x1[3]);
        b[0]=f2bf(x2[0]); b[1]=f2bf(x2[1]); b[2]=f2bf(x2[2]); b[3]=f2bf(x2[3]);
        b[4]=f2bf(x3[0]); b[5]=f2bf(x3[1]); b[6]=f2bf(x3[2]); b[7]=f2bf(x3[3]);
    }
    {
        const int g = h >> 2, i0 = (h & 3) * 2;
        unsigned short* dst = lB + r * K2 + g * 64;
        *(ushort8*)&dst[((i0    ) ^ rx) * 8] = a;
        *(ushort8*)&dst[((i0 + 1) ^ rx) * 8] = b;
    }
    {
        float acc[16];
        #pragma unroll
        for (int e = 0; e < 16; ++e) acc[e] = 0.f;
        #pragma unroll
        for (int s = 0; s < NS; ++s) {
            const f32x4* p = (const f32x4*)(features + (size_t)nidx[s] * FEAT + h * 16);
            f32x4 x0 = p[0], x1 = p[1], x2 = p[2], x3 = p[3];
            #pragma unroll
            for (int e = 0; e < 4; ++e) {
                acc[e]      += x0[e];
                acc[4 + e]  += x1[e];
                acc[8 + e]  += x2[e];
                acc[12 + e] += x3[e];
            }
        }
        ushort8 aa, bb;
        #pragma unroll
        for (int e = 0; e < 8; ++e) {
            aa[e] = f2bf(valid ? acc[e]     * 0.1f : 0.f);
            bb[e] = f2bf(valid ? acc[8 + e] * 0.1f : 0.f);
        }
        const int g = 4 + (h >> 2), i0 = (h & 3) * 2;
        unsigned short* dst = lB + r * K2 + g * 64;
        *(ushort8*)&dst[((i0    ) ^ rx) * 8] = aa;
        *(ushort8*)&dst[((i0 + 1) ^ rx) * 8] = bb;
    }
    __syncthreads();

    const int w    = tid >> 6;
    const int lane = tid & 63;
    const int lr   = lane & 15;
    const int lg   = lane >> 4;

    f32x4 facc[2][2] = {};
    #pragma unroll
    for (int kt = 0; kt < 8; ++kt) {
        bf16x8 af[2][2], bfr[2][2];
        #pragma unroll
        for (int i = 0; i < 2; ++i)
            #pragma unroll
            for (int ks = 0; ks < 2; ++ks)
                af[i][ks] = *(const bf16x8*)(wp +
                    ((((kt * 16 + w * 2 + i) * 2 + ks) * 64 + lane) << 3));
        #pragma unroll
        for (int j = 0; j < 2; ++j) {
            const int rb = j * 16 + lr;
            #pragma unroll
            for (int ks = 0; ks < 2; ++ks) {
                int cc = kt * 8 + ((ks * 4 + lg) ^ (rb & 7));
                bfr[j][ks] = *(const bf16x8*)&lB[rb * K2 + cc * 8];
            }
        }
        #pragma unroll
        for (int ks = 0; ks < 2; ++ks)
            #pragma unroll
            for (int i = 0; i < 2; ++i)
                #pragma unroll
                for (int j = 0; j < 2; ++j)
                    facc[i][j] = __builtin_amdgcn_mfma_f32_16x16x32_bf16(
                        af[i][ks], bfr[j][ks], facc[i][j], 0, 0, 0);
    }
    #pragma unroll
    for (int j = 0; j < 2; ++j) {
        const int n2 = nb0 + j * 16 + lr;
        if (n2 < BATCH) {
            #pragma unroll
            for (int i = 0; i < 2; ++i) {
                int m0 = w * 32 + i * 16 + lg * 4;
                #pragma unroll
                for (int rg = 0; rg < 4; ++rg) {
                    float v = facc[i][j][rg];
                    v = v > 0.f ? v : 0.f;
                    __builtin_nontemporal_store(v, &out[(size_t)(m0 + rg) * BATCH + n2]);
                }
            }
        }
    }
}

extern "C" void kernel_launch(void* const* d_in, const int* in_sizes, int n_in,
                              void* d_out, int out_size, void* d_ws, size_t ws_size,
                              hipStream_t stream) {
    const float* features = (const float*)d_in[0];
    const float* weight   = (const float*)d_in[1];
    const int*   nodes    = (const int*)d_in[2];
    const int*   neigh    = (const int*)d_in[3];
    float* out = (float*)d_out;

    unsigned short* wp   = (unsigned short*)d_ws;                         // 256 KB
    unsigned short* fbf  = wp + (size_t)EMBED * K2;                       // 51.2 MB
    unsigned char*  f8   = (unsigned char*)(fbf + (size_t)NNODES * FEAT); // 25.6 MB
    unsigned short* nm   = (unsigned short*)(f8 + (size_t)NNODES * FEAT); // 25.6 MB

    const size_t need_t2   = (size_t)EMBED * K2 * 2 + (size_t)NNODES * FEAT * 3;
    const size_t need_full = need_t2 + (size_t)NSH * BATCH * SHC * 2;

    wpack_kernel<<<(EMBED * K2 / 8) / 256, 256, 0, stream>>>(weight, wp);

    if (ws_size >= need_full) {
        fconv_kernel<true><<<(NNODES * FEAT / 8) / 256, 256, 0, stream>>>(features, fbf, f8);
        nmean_kernel<<<NSH * ((BATCH + 63) / 64), 256, 0, stream>>>(f8, neigh, nm);
        gemm_xcd<<<NBLK, 512, 0, stream>>>(fbf, nm, wp, nodes, out);
    } else if (ws_size >= need_t2) {
        fconv_kernel<false><<<(NNODES * FEAT / 8) / 256, 256, 0, stream>>>(features, fbf, f8);
        gemm_dma<<<NBLK, 512, 0, stream>>>(fbf, f8, wp, nodes, neigh, out);
    } else {
        gemm_f32<<<NBLK, 512, 0, stream>>>(features, wp, nodes, neigh, out);
    }
}

// Round 10
// 74.199 us; speedup vs baseline: 1.4875x; 1.4875x over previous
//
#include <hip/hip_runtime.h>

#define FEAT   256
#define K2     512      // 2*FEAT
#define NNODES 100000
#define BATCH  50000
#define NS     10
#define EMBED  256
#define BN     32
#define NBLK   ((BATCH + BN - 1) / BN)   // 1563

typedef __attribute__((ext_vector_type(8))) __bf16         bf16x8;
typedef __attribute__((ext_vector_type(8))) unsigned short ushort8;
typedef __attribute__((ext_vector_type(4))) float          f32x4;
typedef __attribute__((ext_vector_type(2))) float          f32x2;
typedef __attribute__((ext_vector_type(2))) int            i32x2;
typedef __attribute__((ext_vector_type(4))) int            i32x4;

static __device__ __forceinline__ unsigned short f2bf(float x) {
    unsigned int u = __builtin_bit_cast(unsigned int, x);
    u += 0x7FFFu + ((u >> 16) & 1u);
    return (unsigned short)(u >> 16);
}

// ---- features f32 -> fp8 e4m3 table ONLY (regular loads: retain features in L3) ----
__global__ void fconv_kernel(const float* __restrict__ f,
                             unsigned char* __restrict__ f8) {
    int i = blockIdx.x * blockDim.x + threadIdx.x;   // one 8-elem chunk
    const f32x4* src = (const f32x4*)(f + (size_t)i * 8);
    f32x4 a = src[0], b = src[1];
    int u0 = 0, u1 = 0;
    u0 = __builtin_amdgcn_cvt_pk_fp8_f32(a[0], a[1], u0, false);
    u0 = __builtin_amdgcn_cvt_pk_fp8_f32(a[2], a[3], u0, true);
    u1 = __builtin_amdgcn_cvt_pk_fp8_f32(b[0], b[1], u1, false);
    u1 = __builtin_amdgcn_cvt_pk_fp8_f32(b[2], b[3], u1, true);
    i32x2 p; p[0] = u0; p[1] = u1;
    ((i32x2*)f8)[i] = p;
}

// ---- weight f32 -> bf16, fragment-major: [kt(8)][mblk(16)][ks(2)][lane(64)][8] ----
__global__ void wpack_kernel(const float* __restrict__ w,
                             unsigned short* __restrict__ wp) {
    int c    = blockIdx.x * blockDim.x + threadIdx.x;  // 16384 chunks
    int lane = c & 63;
    int ks   = (c >> 6) & 1;
    int mblk = (c >> 7) & 15;
    int kt   = c >> 11;
    int row  = mblk * 16 + (lane & 15);
    int col  = kt * 64 + ks * 32 + (lane >> 4) * 8;
    const f32x4* src = (const f32x4*)(w + row * K2 + col);
    f32x4 a = src[0], b = src[1];
    ushort8 h;
    h[0]=f2bf(a[0]); h[1]=f2bf(a[1]); h[2]=f2bf(a[2]); h[3]=f2bf(a[3]);
    h[4]=f2bf(b[0]); h[5]=f2bf(b[1]); h[6]=f2bf(b[2]); h[7]=f2bf(b[3]);
    ((ushort8*)wp)[c] = h;
}

// ---- fused: self from f32 features (L3-hot), neighbor from fp8 table, MFMA, relu ----
// LDS tile lB[32][512] bf16, XOR swizzle: 8-col chunk index low3 ^= (row&7)
__global__ __launch_bounds__(512, 4) void gemm_hyb(
    const float* __restrict__ features,
    const unsigned char* __restrict__ f8,
    const unsigned short* __restrict__ wp,
    const int* __restrict__ nodes,
    const int* __restrict__ neigh,
    float* __restrict__ out) {

    __shared__ __align__(16) unsigned short lB[BN * K2];   // 32 KB

    const int tid = threadIdx.x;
    const int nb0 = blockIdx.x * BN;
    const int r   = tid >> 4;     // 0..31 row in tile
    const int p   = tid & 15;     // 16-col span
    const int rx  = r & 7;
    const int n   = min(nb0 + r, BATCH - 1);   // clamp; store is guarded

    // ---- self half: gather f32 row directly (fconv just streamed features -> L3) ----
    {
        const int node0 = nodes[n];
        const f32x4* s0 = (const f32x4*)(features + (size_t)node0 * FEAT + p * 16);
        f32x4 x0 = s0[0], x1 = s0[1], x2 = s0[2], x3 = s0[3];
        ushort8 a, b;
        a[0]=f2bf(x0[0]); a[1]=f2bf(x0[1]); a[2]=f2bf(x0[2]); a[3]=f2bf(x0[3]);
        a[4]=f2bf(x1[0]); a[5]=f2bf(x1[1]); a[6]=f2bf(x1[2]); a[7]=f2bf(x1[3]);
        b[0]=f2bf(x2[0]); b[1]=f2bf(x2[1]); b[2]=f2bf(x2[2]); b[3]=f2bf(x2[3]);
        b[4]=f2bf(x3[0]); b[5]=f2bf(x3[1]); b[6]=f2bf(x3[2]); b[7]=f2bf(x3[3]);
        const int g = p >> 2, i0 = (p & 3) * 2;
        unsigned short* dst = lB + r * K2 + g * 64;
        *(ushort8*)&dst[((i0    ) ^ rx) * 8] = a;
        *(ushort8*)&dst[((i0 + 1) ^ rx) * 8] = b;
    }

    // ---- neighbor half: fp8 rows (256 B), one 16 B piece per thread per sample ----
    {
        int idx[NS];
        #pragma unroll
        for (int s = 0; s < NS; ++s) idx[s] = neigh[n * NS + s];

        float acc[16];
        #pragma unroll
        for (int e = 0; e < 16; ++e) acc[e] = 0.f;

        #pragma unroll
        for (int s = 0; s < NS; ++s) {
            i32x4 v = *(const i32x4*)(f8 + (size_t)idx[s] * FEAT + p * 16);
            #pragma unroll
            for (int q = 0; q < 4; ++q) {
                f32x2 lo = __builtin_amdgcn_cvt_pk_f32_fp8(v[q], false);
                f32x2 hi = __builtin_amdgcn_cvt_pk_f32_fp8(v[q], true);
                acc[q * 4 + 0] += lo[0];
                acc[q * 4 + 1] += lo[1];
                acc[q * 4 + 2] += hi[0];
                acc[q * 4 + 3] += hi[1];
            }
        }
        ushort8 a, b;
        #pragma unroll
        for (int e = 0; e < 8; ++e) {
            a[e] = f2bf(acc[e]     * 0.1f);
            b[e] = f2bf(acc[8 + e] * 0.1f);
        }
        const int g = 4 + (p >> 2), i0 = (p & 3) * 2;
        unsigned short* dst = lB + r * K2 + g * 64;
        *(ushort8*)&dst[((i0    ) ^ rx) * 8] = a;
        *(ushort8*)&dst[((i0 + 1) ^ rx) * 8] = b;
    }
    __syncthreads();

    // ---- MFMA: 8 waves, wave w -> m rows [w*32, w*32+32), all 32 n-cols ----
    const int w    = tid >> 6;
    const int lane = tid & 63;
    const int lr   = lane & 15;
    const int lg   = lane >> 4;

    f32x4 facc[2][2] = {};

    #pragma unroll
    for (int kt = 0; kt < 8; ++kt) {
        bf16x8 af[2][2], bfr[2][2];
        #pragma unroll
        for (int i = 0; i < 2; ++i)
            #pragma unroll
            for (int ks = 0; ks < 2; ++ks)
                af[i][ks] = *(const bf16x8*)(wp +
                    ((((kt * 16 + w * 2 + i) * 2 + ks) * 64 + lane) << 3));
        #pragma unroll
        for (int j = 0; j < 2; ++j) {
            const int rb = j * 16 + lr;
            #pragma unroll
            for (int ks = 0; ks < 2; ++ks) {
                int cc = kt * 8 + ((ks * 4 + lg) ^ (rb & 7));
                bfr[j][ks] = *(const bf16x8*)&lB[rb * K2 + cc * 8];
            }
        }
        #pragma unroll
        for (int ks = 0; ks < 2; ++ks)
            #pragma unroll
            for (int i = 0; i < 2; ++i)
                #pragma unroll
                for (int j = 0; j < 2; ++j)
                    facc[i][j] = __builtin_amdgcn_mfma_f32_16x16x32_bf16(
                        af[i][ks], bfr[j][ks], facc[i][j], 0, 0, 0);
    }

    // ---- epilogue: relu + nt store. C/D: col=lane&15, row=(lane>>4)*4+reg ----
    #pragma unroll
    for (int j = 0; j < 2; ++j) {
        const int n2 = nb0 + j * 16 + lr;
        if (n2 < BATCH) {
            #pragma unroll
            for (int i = 0; i < 2; ++i) {
                int m0 = w * 32 + i * 16 + lg * 4;
                #pragma unroll
                for (int rg = 0; rg < 4; ++rg) {
                    float v = facc[i][j][rg];
                    v = v > 0.f ? v : 0.f;
                    __builtin_nontemporal_store(v, &out[(size_t)(m0 + rg) * BATCH + n2]);
                }
            }
        }
    }
}

// ---- fallback (ws too small): all-f32 gather ----
__global__ __launch_bounds__(512, 4) void gemm_f32(
    const float* __restrict__ features,
    const unsigned short* __restrict__ wp,
    const int* __restrict__ nodes,
    const int* __restrict__ neigh,
    float* __restrict__ out) {

    __shared__ __align__(16) unsigned short lB[BN * K2];

    const int tid = threadIdx.x;
    const int nb0 = blockIdx.x * BN;
    const int r  = tid >> 4;
    const int h  = tid & 15;
    const int rx = r & 7;
    const int n  = min(nb0 + r, BATCH - 1);

    int node0 = nodes[n];
    int nidx[NS];
    #pragma unroll
    for (int s = 0; s < NS; ++s) nidx[s] = neigh[n * NS + s];

    {
        const f32x4* s0 = (const f32x4*)(features + (size_t)node0 * FEAT + h * 16);
        f32x4 x0 = s0[0], x1 = s0[1], x2 = s0[2], x3 = s0[3];
        ushort8 a, b;
        a[0]=f2bf(x0[0]); a[1]=f2bf(x0[1]); a[2]=f2bf(x0[2]); a[3]=f2bf(x0[3]);
        a[4]=f2bf(x1[0]); a[5]=f2bf(x1[1]); a[6]=f2bf(x1[2]); a[7]=f2bf(x1[3]);
        b[0]=f2bf(x2[0]); b[1]=f2bf(x2[1]); b[2]=f2bf(x2[2]); b[3]=f2bf(x2[3]);
        b[4]=f2bf(x3[0]); b[5]=f2bf(x3[1]); b[6]=f2bf(x3[2]); b[7]=f2bf(x3[3]);
        const int g = h >> 2, i0 = (h & 3) * 2;
        unsigned short* dst = lB + r * K2 + g * 64;
        *(ushort8*)&dst[((i0    ) ^ rx) * 8] = a;
        *(ushort8*)&dst[((i0 + 1) ^ rx) * 8] = b;
    }
    {
        float acc[16];
        #pragma unroll
        for (int e = 0; e < 16; ++e) acc[e] = 0.f;
        #pragma unroll
        for (int s = 0; s < NS; ++s) {
            const f32x4* pp = (const f32x4*)(features + (size_t)nidx[s] * FEAT + h * 16);
            f32x4 x0 = pp[0], x1 = pp[1], x2 = pp[2], x3 = pp[3];
            #pragma unroll
            for (int e = 0; e < 4; ++e) {
                acc[e]      += x0[e];
                acc[4 + e]  += x1[e];
                acc[8 + e]  += x2[e];
                acc[12 + e] += x3[e];
            }
        }
        ushort8 aa, bb;
        #pragma unroll
        for (int e = 0; e < 8; ++e) {
            aa[e] = f2bf(acc[e]     * 0.1f);
            bb[e] = f2bf(acc[8 + e] * 0.1f);
        }
        const int g = 4 + (h >> 2), i0 = (h & 3) * 2;
        unsigned short* dst = lB + r * K2 + g * 64;
        *(ushort8*)&dst[((i0    ) ^ rx) * 8] = aa;
        *(ushort8*)&dst[((i0 + 1) ^ rx) * 8] = bb;
    }
    __syncthreads();

    const int w    = tid >> 6;
    const int lane = tid & 63;
    const int lr   = lane & 15;
    const int lg   = lane >> 4;

    f32x4 facc[2][2] = {};
    #pragma unroll
    for (int kt = 0; kt < 8; ++kt) {
        bf16x8 af[2][2], bfr[2][2];
        #pragma unroll
        for (int i = 0; i < 2; ++i)
            #pragma unroll
            for (int ks = 0; ks < 2; ++ks)
                af[i][ks] = *(const bf16x8*)(wp +
                    ((((kt * 16 + w * 2 + i) * 2 + ks) * 64 + lane) << 3));
        #pragma unroll
        for (int j = 0; j < 2; ++j) {
            const int rb = j * 16 + lr;
            #pragma unroll
            for (int ks = 0; ks < 2; ++ks) {
                int cc = kt * 8 + ((ks * 4 + lg) ^ (rb & 7));
                bfr[j][ks] = *(const bf16x8*)&lB[rb * K2 + cc * 8];
            }
        }
        #pragma unroll
        for (int ks = 0; ks < 2; ++ks)
            #pragma unroll
            for (int i = 0; i < 2; ++i)
                #pragma unroll
                for (int j = 0; j < 2; ++j)
                    facc[i][j] = __builtin_amdgcn_mfma_f32_16x16x32_bf16(
                        af[i][ks], bfr[j][ks], facc[i][j], 0, 0, 0);
    }
    #pragma unroll
    for (int j = 0; j < 2; ++j) {
        const int n2 = nb0 + j * 16 + lr;
        if (n2 < BATCH) {
            #pragma unroll
            for (int i = 0; i < 2; ++i) {
                int m0 = w * 32 + i * 16 + lg * 4;
                #pragma unroll
                for (int rg = 0; rg < 4; ++rg) {
                    float v = facc[i][j][rg];
                    v = v > 0.f ? v : 0.f;
                    __builtin_nontemporal_store(v, &out[(size_t)(m0 + rg) * BATCH + n2]);
                }
            }
        }
    }
}

extern "C" void kernel_launch(void* const* d_in, const int* in_sizes, int n_in,
                              void* d_out, int out_size, void* d_ws, size_t ws_size,
                              hipStream_t stream) {
    const float* features = (const float*)d_in[0];
    const float* weight   = (const float*)d_in[1];
    const int*   nodes    = (const int*)d_in[2];
    const int*   neigh    = (const int*)d_in[3];
    float* out = (float*)d_out;

    unsigned short* wp = (unsigned short*)d_ws;                 // 256 KB packed weight
    unsigned char*  f8 = (unsigned char*)(wp + (size_t)EMBED * K2); // 25.6 MB fp8 table

    const size_t need = (size_t)EMBED * K2 * 2 + (size_t)NNODES * FEAT;

    wpack_kernel<<<(EMBED * K2 / 8) / 256, 256, 0, stream>>>(weight, wp);

    if (ws_size >= need) {
        fconv_kernel<<<(NNODES * FEAT / 8) / 256, 256, 0, stream>>>(features, f8);
        gemm_hyb<<<NBLK, 512, 0, stream>>>(features, f8, wp, nodes, neigh, out);
    } else {
        gemm_f32<<<NBLK, 512, 0, stream>>>(features, wp, nodes, neigh, out);
    }
}